// Round 1
// baseline (187.651 us; speedup 1.0000x reference)
//
#include <hip/hip_runtime.h>
#include <math.h>

#define N    8192
#define FIN  94
#define FOUT 16
#define ALPHA 0.2f
#define RPB  4   // rows per block in main kernel

// ws layout (float32 elements)
#define WH_OFF   0         // 8192*16 = 131072
#define SSRC_OFF 131072    // 8192
#define SDST_OFF 139264    // 8192
#define M_OFF    147456    // 1

typedef int   i32x4 __attribute__((ext_vector_type(4)));
typedef float f32x4 __attribute__((ext_vector_type(4)));

// Kernel 1: Wh = h @ W  (8192x16), plus s_src = Wh@a1, s_dst = Wh@a2.
// One thread per (row, col) output element; 16 threads of a row then
// quarter-group shuffle-reduce the score dot products.
__global__ __launch_bounds__(256) void wh_score_kernel(
    const float* __restrict__ h, const float* __restrict__ W,
    const float* __restrict__ attn, float* __restrict__ ws)
{
    const int gid = blockIdx.x * 256 + threadIdx.x;  // 0..131071
    const int i = gid >> 4;
    const int k = gid & 15;
    const float* hrow = h + i * FIN;
    float acc = 0.0f;
    #pragma unroll 2
    for (int c = 0; c < FIN; ++c)
        acc = fmaf(hrow[c], W[c * FOUT + k], acc);
    ws[WH_OFF + gid] = acc;

    float ps = acc * attn[k];
    float pd = acc * attn[FOUT + k];
    #pragma unroll
    for (int mk = 1; mk < 16; mk <<= 1) {
        ps += __shfl_xor(ps, mk);
        pd += __shfl_xor(pd, mk);
    }
    if (k == 0) {
        ws[SSRC_OFF + i] = ps;
        ws[SDST_OFF + i] = pd;
    }
}

// Kernel 2: global max of s_dst (single block).
__global__ __launch_bounds__(256) void max_kernel(float* __restrict__ ws)
{
    __shared__ float red[4];
    float m = -1e30f;
    for (int i = threadIdx.x; i < N; i += 256)
        m = fmaxf(m, ws[SDST_OFF + i]);
    #pragma unroll
    for (int mk = 1; mk < 64; mk <<= 1)
        m = fmaxf(m, __shfl_xor(m, mk));
    const int lane = threadIdx.x & 63;
    const int wave = threadIdx.x >> 6;
    if (lane == 0) red[wave] = m;
    __syncthreads();
    if (threadIdx.x == 0)
        ws[M_OFF] = fmaxf(fmaxf(red[0], red[1]), fmaxf(red[2], red[3]));
}

// Kernel 3: fused masked-softmax + att@Wh + ELU.
// Block = 256 threads, handles RPB rows x all 8192 cols.
// Each thread: 8 iterations x 4 consecutive j.  adj loads are int4,
// nontemporal (streamed once).  Wh[j] (64B) loaded once per block,
// reused for RPB rows in registers.
__global__ __launch_bounds__(256) void gat_main_kernel(
    const int* __restrict__ adj, const float* __restrict__ ws,
    float* __restrict__ out)
{
    const int tid = threadIdx.x;
    const int i0 = blockIdx.x * RPB;

    const float Mg = ws[M_OFF];
    float ss[RPB], mrow[RPB];
    #pragma unroll
    for (int r = 0; r < RPB; ++r) {
        ss[r] = ws[SSRC_OFF + i0 + r];
        const float x = ss[r] + Mg;
        mrow[r] = fmaxf(x, ALPHA * x);   // leaky_relu upper bound of row max
    }

    float acc[RPB][FOUT];
    float lsum[RPB];
    #pragma unroll
    for (int r = 0; r < RPB; ++r) {
        lsum[r] = 0.0f;
        #pragma unroll
        for (int c = 0; c < FOUT; ++c) acc[r][c] = 0.0f;
    }

    const float* __restrict__ Wh   = ws + WH_OFF;
    const float* __restrict__ sdst = ws + SDST_OFF;

    #pragma unroll 1
    for (int s = 0; s < N / (256 * 4); ++s) {
        const int j = (s * 256 + tid) * 4;
        i32x4 arow[RPB];
        #pragma unroll
        for (int r = 0; r < RPB; ++r)
            arow[r] = __builtin_nontemporal_load(
                (const i32x4*)(adj + (size_t)(i0 + r) * N + j));
        const f32x4 sd4 = *(const f32x4*)(sdst + j);

        #pragma unroll
        for (int q = 0; q < 4; ++q) {
            const int jj = j + q;
            const f32x4* whp = (const f32x4*)(Wh + jj * FOUT);
            const f32x4 wh0 = whp[0], wh1 = whp[1], wh2 = whp[2], wh3 = whp[3];
            const float sd = sd4[q];
            #pragma unroll
            for (int r = 0; r < RPB; ++r) {
                const float x = ss[r] + sd;
                const float e = fmaxf(x, ALPHA * x);   // leaky_relu
                const float w = (arow[r][q] > 0) ? __expf(e - mrow[r]) : 0.0f;
                lsum[r] += w;
                #pragma unroll
                for (int c = 0; c < 4; ++c) {
                    acc[r][c]      = fmaf(w, wh0[c], acc[r][c]);
                    acc[r][4 + c]  = fmaf(w, wh1[c], acc[r][4 + c]);
                    acc[r][8 + c]  = fmaf(w, wh2[c], acc[r][8 + c]);
                    acc[r][12 + c] = fmaf(w, wh3[c], acc[r][12 + c]);
                }
            }
        }
    }

    // Reduce 256 threads -> row sums.  Intra-wave butterfly first.
    #pragma unroll
    for (int mk = 1; mk < 64; mk <<= 1) {
        #pragma unroll
        for (int r = 0; r < RPB; ++r) {
            lsum[r] += __shfl_xor(lsum[r], mk);
            #pragma unroll
            for (int c = 0; c < FOUT; ++c)
                acc[r][c] += __shfl_xor(acc[r][c], mk);
        }
    }

    __shared__ float red[4][RPB][FOUT + 1];
    const int wave = tid >> 6;
    const int lane = tid & 63;
    if (lane == 0) {
        #pragma unroll
        for (int r = 0; r < RPB; ++r) {
            red[wave][r][FOUT] = lsum[r];
            #pragma unroll
            for (int c = 0; c < FOUT; ++c) red[wave][r][c] = acc[r][c];
        }
    }
    __syncthreads();

    if (tid < RPB * FOUT) {
        const int r = tid >> 4;
        const int c = tid & 15;
        const float A = red[0][r][c] + red[1][r][c] + red[2][r][c] + red[3][r][c];
        const float L = red[0][r][FOUT] + red[1][r][FOUT] +
                        red[2][r][FOUT] + red[3][r][FOUT];
        const float v = A / L;
        out[(i0 + r) * FOUT + c] = (v > 0.0f) ? v : expm1f(v);   // ELU
    }
}

extern "C" void kernel_launch(void* const* d_in, const int* in_sizes, int n_in,
                              void* d_out, int out_size, void* d_ws, size_t ws_size,
                              hipStream_t stream)
{
    const float* h    = (const float*)d_in[0];
    const int*   adj  = (const int*)d_in[1];
    const float* W    = (const float*)d_in[2];
    const float* attn = (const float*)d_in[3];
    float* out = (float*)d_out;
    float* ws  = (float*)d_ws;

    wh_score_kernel<<<(N * FOUT) / 256, 256, 0, stream>>>(h, W, attn, ws);
    max_kernel<<<1, 256, 0, stream>>>(ws);
    gat_main_kernel<<<N / RPB, 256, 0, stream>>>(adj, ws, out);
}

// Round 2
// 124.424 us; speedup vs baseline: 1.5082x; 1.5082x over previous
//
#include <hip/hip_runtime.h>
#include <math.h>

#define N      8192
#define FIN    94
#define FOUT   16
#define ALPHA  0.2f
#define RPB    4
#define TJ     1024
#define NTILES (N / TJ)

// ws float offsets
#define WHT_OFF  0                 // Wh_t[16][8192] (transposed)
#define SSRC_OFF (16 * N)
#define B_OFF    (SSRC_OFF + N)    // exp(sd_j)
#define D_OFF    (B_OFF + N)       // exp(0.2*sd_j)
#define M_OFF    (D_OFF + N)       // log(max B) = max sd

typedef int   i32x4 __attribute__((ext_vector_type(4)));
typedef float f32x4 __attribute__((ext_vector_type(4)));

// Kernel 1: Wh (stored transposed), s_src, B=exp(s_dst), D=exp(0.2*s_dst).
__global__ __launch_bounds__(256) void wh_score_kernel(
    const float* __restrict__ h, const float* __restrict__ W,
    const float* __restrict__ attn, float* __restrict__ ws)
{
    const int gid = blockIdx.x * 256 + threadIdx.x;  // 0..131071
    const int i = gid >> 4;
    const int k = gid & 15;
    const float* hrow = h + i * FIN;
    float acc = 0.0f;
    #pragma unroll 2
    for (int c = 0; c < FIN; ++c)
        acc = fmaf(hrow[c], W[c * FOUT + k], acc);
    ws[WHT_OFF + k * N + i] = acc;   // transposed store

    float ps = acc * attn[k];
    float pd = acc * attn[FOUT + k];
    #pragma unroll
    for (int mk = 1; mk < 16; mk <<= 1) {
        ps += __shfl_xor(ps, mk);
        pd += __shfl_xor(pd, mk);
    }
    if (k == 0) {
        ws[SSRC_OFF + i] = ps;
        ws[B_OFF + i] = __expf(pd);
        ws[D_OFF + i] = __expf(ALPHA * pd);
    }
}

// Kernel 2: global max of B -> store log(maxB) (= max s_dst).
__global__ __launch_bounds__(256) void max_kernel(float* __restrict__ ws)
{
    __shared__ float red[4];
    float m = 0.0f;  // B > 0
    for (int i = threadIdx.x; i < N; i += 256)
        m = fmaxf(m, ws[B_OFF + i]);
    #pragma unroll
    for (int mk = 1; mk < 64; mk <<= 1)
        m = fmaxf(m, __shfl_xor(m, mk));
    const int lane = threadIdx.x & 63;
    const int wave = threadIdx.x >> 6;
    if (lane == 0) red[wave] = m;
    __syncthreads();
    if (threadIdx.x == 0)
        ws[M_OFF] = logf(fmaxf(fmaxf(red[0], red[1]), fmaxf(red[2], red[3])));
}

// Kernel 3: fused masked-softmax + att@Wh + ELU.
// w_ij = mask * (x>0 ? A_i*B_j : C_i*D_j),  x = ss_i + sd_j,
// pos test via monotone exp: B_j > exp(-ss_i).
__global__ __launch_bounds__(256, 3) void gat_main_kernel(
    const int* __restrict__ adj, const float* __restrict__ ws,
    float* __restrict__ out)
{
    const int tid = threadIdx.x;
    const int i0 = blockIdx.x * RPB;
    const int col = tid * 4;

    const float Mg = ws[M_OFF];
    float Ar[RPB], Cr[RPB], Bt[RPB], lsum[RPB];
    float acc[RPB][FOUT];
    #pragma unroll
    for (int r = 0; r < RPB; ++r) {
        const float ss = ws[SSRC_OFF + i0 + r];
        const float x = ss + Mg;
        const float m = fmaxf(x, ALPHA * x);
        Ar[r] = __expf(ss - m);
        Cr[r] = __expf(ALPHA * ss - m);
        Bt[r] = __expf(-ss);
        lsum[r] = 0.0f;
        #pragma unroll
        for (int c = 0; c < FOUT; ++c) acc[r][c] = 0.0f;
    }

    const float* __restrict__ wht = ws + WHT_OFF;
    const float* __restrict__ Bp  = ws + B_OFF;
    const float* __restrict__ Dp  = ws + D_OFF;

    // prefetch tile 0
    i32x4 a_cur[RPB], a_nxt[RPB];
    f32x4 B_cur, D_cur, B_nxt, D_nxt;
    #pragma unroll
    for (int r = 0; r < RPB; ++r)
        a_cur[r] = __builtin_nontemporal_load(
            (const i32x4*)(adj + (size_t)(i0 + r) * N + col));
    B_cur = *(const f32x4*)(Bp + col);
    D_cur = *(const f32x4*)(Dp + col);

    #pragma unroll 1
    for (int t = 0; t < NTILES; ++t) {
        const int jb = t * TJ;
        if (t + 1 < NTILES) {
            #pragma unroll
            for (int r = 0; r < RPB; ++r)
                a_nxt[r] = __builtin_nontemporal_load(
                    (const i32x4*)(adj + (size_t)(i0 + r) * N + jb + TJ + col));
            B_nxt = *(const f32x4*)(Bp + jb + TJ + col);
            D_nxt = *(const f32x4*)(Dp + jb + TJ + col);
        }

        // attention weights for this thread's 4 j's x RPB rows
        float w[RPB][4];
        #pragma unroll
        for (int q = 0; q < 4; ++q) {
            const float Bq = B_cur[q], Dq = D_cur[q];
            #pragma unroll
            for (int r = 0; r < RPB; ++r) {
                const bool pos = Bq > Bt[r];
                const float S = pos ? Ar[r] : Cr[r];
                const float P = pos ? Bq : Dq;
                const float ww = (a_cur[r][q] > 0) ? S * P : 0.0f;
                w[r][q] = ww;
                lsum[r] += ww;
            }
        }

        // coalesced Wh_t loads (quarters to bound registers) + FMAs
        #pragma unroll
        for (int qt = 0; qt < 4; ++qt) {
            f32x4 v[4];
            #pragma unroll
            for (int c4 = 0; c4 < 4; ++c4)
                v[c4] = *(const f32x4*)(wht + (qt * 4 + c4) * N + jb + col);
            #pragma unroll
            for (int q = 0; q < 4; ++q) {
                #pragma unroll
                for (int c4 = 0; c4 < 4; ++c4) {
                    const float vv = v[c4][q];
                    #pragma unroll
                    for (int r = 0; r < RPB; ++r)
                        acc[r][qt * 4 + c4] = fmaf(w[r][q], vv, acc[r][qt * 4 + c4]);
                }
            }
        }

        #pragma unroll
        for (int r = 0; r < RPB; ++r) a_cur[r] = a_nxt[r];
        B_cur = B_nxt;
        D_cur = D_nxt;
    }

    // Reduce across 64 lanes, then across 4 waves via LDS.
    #pragma unroll
    for (int mk = 1; mk < 64; mk <<= 1) {
        #pragma unroll
        for (int r = 0; r < RPB; ++r) {
            lsum[r] += __shfl_xor(lsum[r], mk);
            #pragma unroll
            for (int c = 0; c < FOUT; ++c)
                acc[r][c] += __shfl_xor(acc[r][c], mk);
        }
    }

    __shared__ float red[4][RPB][FOUT + 1];
    const int wave = tid >> 6;
    const int lane = tid & 63;
    if (lane == 0) {
        #pragma unroll
        for (int r = 0; r < RPB; ++r) {
            red[wave][r][FOUT] = lsum[r];
            #pragma unroll
            for (int c = 0; c < FOUT; ++c) red[wave][r][c] = acc[r][c];
        }
    }
    __syncthreads();

    if (tid < RPB * FOUT) {
        const int r = tid >> 4;
        const int c = tid & 15;
        const float A = red[0][r][c] + red[1][r][c] + red[2][r][c] + red[3][r][c];
        const float L = red[0][r][FOUT] + red[1][r][FOUT] +
                        red[2][r][FOUT] + red[3][r][FOUT];
        const float v = A / L;
        out[(i0 + r) * FOUT + c] = (v > 0.0f) ? v : expm1f(v);   // ELU
    }
}

extern "C" void kernel_launch(void* const* d_in, const int* in_sizes, int n_in,
                              void* d_out, int out_size, void* d_ws, size_t ws_size,
                              hipStream_t stream)
{
    const float* h    = (const float*)d_in[0];
    const int*   adj  = (const int*)d_in[1];
    const float* W    = (const float*)d_in[2];
    const float* attn = (const float*)d_in[3];
    float* out = (float*)d_out;
    float* ws  = (float*)d_ws;

    wh_score_kernel<<<(N * FOUT) / 256, 256, 0, stream>>>(h, W, attn, ws);
    max_kernel<<<1, 256, 0, stream>>>(ws);
    gat_main_kernel<<<N / RPB, 256, 0, stream>>>(adj, ws, out);
}

// Round 3
// 115.413 us; speedup vs baseline: 1.6259x; 1.0781x over previous
//
#include <hip/hip_runtime.h>
#include <hip/hip_bf16.h>
#include <math.h>

#define N      8192
#define FIN    94
#define FOUT   16
#define ALPHA  0.2f
#define RPB    4
#define TJ     1024
#define NTILES (N / TJ)

// ws layout: bf16 Wh_t[16][8192] at byte 0 (256 KB), then f32 arrays.
#define F32_BASE  65536          // float-index where f32 region starts
#define AR_OFF   (F32_BASE)          // exp(s_src)
#define CR_OFF   (F32_BASE + N)      // exp(0.2*s_src)
#define BT_OFF   (F32_BASE + 2*N)    // exp(-s_src)
#define BX_OFF   (F32_BASE + 3*N)    // exp(s_dst)
#define DX_OFF   (F32_BASE + 4*N)    // exp(0.2*s_dst)

typedef int          i32x4 __attribute__((ext_vector_type(4)));
typedef float        f32x4 __attribute__((ext_vector_type(4)));
typedef unsigned int u32x2 __attribute__((ext_vector_type(2)));

// Kernel 1: Wh (bf16, transposed) + all five exp tables.
__global__ __launch_bounds__(256) void wh_score_kernel(
    const float* __restrict__ h, const float* __restrict__ W,
    const float* __restrict__ attn, float* __restrict__ ws)
{
    const int gid = blockIdx.x * 256 + threadIdx.x;  // 0..131071
    const int i = gid >> 4;
    const int k = gid & 15;
    const float* hrow = h + i * FIN;
    float a0 = 0.f, a1 = 0.f, a2 = 0.f, a3 = 0.f;
    #pragma unroll
    for (int c = 0; c < 92; c += 4) {
        a0 = fmaf(hrow[c],     W[c * FOUT + k],       a0);
        a1 = fmaf(hrow[c + 1], W[(c + 1) * FOUT + k], a1);
        a2 = fmaf(hrow[c + 2], W[(c + 2) * FOUT + k], a2);
        a3 = fmaf(hrow[c + 3], W[(c + 3) * FOUT + k], a3);
    }
    a0 = fmaf(hrow[92], W[92 * FOUT + k], a0);
    a1 = fmaf(hrow[93], W[93 * FOUT + k], a1);
    const float acc = (a0 + a1) + (a2 + a3);

    __hip_bfloat16* whtb = (__hip_bfloat16*)ws;
    whtb[k * N + i] = __float2bfloat16(acc);   // transposed bf16 store

    float ps = acc * attn[k];
    float pd = acc * attn[FOUT + k];
    #pragma unroll
    for (int mk = 1; mk < 16; mk <<= 1) {
        ps += __shfl_xor(ps, mk);
        pd += __shfl_xor(pd, mk);
    }
    if (k == 0) {
        // No max-shift needed: |scores| <= ~10, exp() safe in f32,
        // softmax is shift-invariant.
        ws[AR_OFF + i] = __expf(ps);
        ws[CR_OFF + i] = __expf(ALPHA * ps);
        ws[BT_OFF + i] = __expf(-ps);
        ws[BX_OFF + i] = __expf(pd);
        ws[DX_OFF + i] = __expf(ALPHA * pd);
    }
}

// Kernel 2: fused masked-softmax + att@Wh + ELU, full register double-buffer.
// w_ij = mask * (x>0 ? A_i*B_j : C_i*D_j), x = ss_i + sd_j; pos test B_j > exp(-ss_i).
__global__ __launch_bounds__(256, 2) void gat_main_kernel(
    const int* __restrict__ adj, const float* __restrict__ ws,
    float* __restrict__ out)
{
    const int tid = threadIdx.x;
    const int i0 = blockIdx.x * RPB;
    const int col = tid * 4;

    const float* __restrict__ Bp = ws + BX_OFF;
    const float* __restrict__ Dp = ws + DX_OFF;
    const unsigned short* __restrict__ whtb = (const unsigned short*)ws;

    float Ar[RPB], Cr[RPB], Bt[RPB], lsum[RPB];
    float acc[RPB][FOUT];
    #pragma unroll
    for (int r = 0; r < RPB; ++r) {
        Ar[r] = ws[AR_OFF + i0 + r];
        Cr[r] = ws[CR_OFF + i0 + r];
        Bt[r] = ws[BT_OFF + i0 + r];
        lsum[r] = 0.0f;
        #pragma unroll
        for (int c = 0; c < FOUT; ++c) acc[r][c] = 0.0f;
    }

    i32x4 aA[RPB], aB[RPB];
    f32x4 B4A, D4A, B4B, D4B;
    u32x2 wA[FOUT], wB[FOUT];

#define ISSUE(ab, B4, D4, wv, t) do {                                          \
    const int jb_ = (t) * TJ + col;                                            \
    _Pragma("unroll") for (int r = 0; r < RPB; ++r)                            \
        (ab)[r] = __builtin_nontemporal_load(                                  \
            (const i32x4*)(adj + (size_t)(i0 + r) * N + jb_));                 \
    (B4) = *(const f32x4*)(Bp + jb_);                                          \
    (D4) = *(const f32x4*)(Dp + jb_);                                          \
    _Pragma("unroll") for (int c = 0; c < FOUT; ++c)                           \
        (wv)[c] = *(const u32x2*)(whtb + c * N + jb_);                         \
} while (0)

#define COMPUTE(ab, B4, D4, wv) do {                                           \
    float w_[RPB][4];                                                          \
    _Pragma("unroll") for (int q = 0; q < 4; ++q) {                            \
        const float Bq = (B4)[q], Dq = (D4)[q];                                \
        _Pragma("unroll") for (int r = 0; r < RPB; ++r) {                      \
            const bool pos = Bq > Bt[r];                                       \
            const float S = pos ? Ar[r] : Cr[r];                               \
            const float P = pos ? Bq : Dq;                                     \
            const float ww = ((ab)[r][q] > 0) ? S * P : 0.0f;                  \
            w_[r][q] = ww;                                                     \
            lsum[r] += ww;                                                     \
        }                                                                      \
    }                                                                          \
    _Pragma("unroll") for (int c = 0; c < FOUT; ++c) {                         \
        const unsigned int lo = (wv)[c][0], hi = (wv)[c][1];                   \
        const float f0 = __uint_as_float(lo << 16);                            \
        const float f1 = __uint_as_float(lo & 0xffff0000u);                    \
        const float f2 = __uint_as_float(hi << 16);                            \
        const float f3 = __uint_as_float(hi & 0xffff0000u);                    \
        _Pragma("unroll") for (int r = 0; r < RPB; ++r) {                      \
            acc[r][c] = fmaf(w_[r][0], f0, acc[r][c]);                         \
            acc[r][c] = fmaf(w_[r][1], f1, acc[r][c]);                         \
            acc[r][c] = fmaf(w_[r][2], f2, acc[r][c]);                         \
            acc[r][c] = fmaf(w_[r][3], f3, acc[r][c]);                         \
        }                                                                      \
    }                                                                          \
} while (0)

    ISSUE(aA, B4A, D4A, wA, 0);
    #pragma unroll 1
    for (int t = 0; t < NTILES; t += 2) {
        ISSUE(aB, B4B, D4B, wB, t + 1);          // t+1 <= 7 always valid
        COMPUTE(aA, B4A, D4A, wA);
        if (t + 2 < NTILES) ISSUE(aA, B4A, D4A, wA, t + 2);
        COMPUTE(aB, B4B, D4B, wB);
    }

    // Reduce across 64 lanes, then across 4 waves via LDS.
    #pragma unroll
    for (int mk = 1; mk < 64; mk <<= 1) {
        #pragma unroll
        for (int r = 0; r < RPB; ++r) {
            lsum[r] += __shfl_xor(lsum[r], mk);
            #pragma unroll
            for (int c = 0; c < FOUT; ++c)
                acc[r][c] += __shfl_xor(acc[r][c], mk);
        }
    }

    __shared__ float red[4][RPB][FOUT + 1];
    const int wave = tid >> 6;
    const int lane = tid & 63;
    if (lane == 0) {
        #pragma unroll
        for (int r = 0; r < RPB; ++r) {
            red[wave][r][FOUT] = lsum[r];
            #pragma unroll
            for (int c = 0; c < FOUT; ++c) red[wave][r][c] = acc[r][c];
        }
    }
    __syncthreads();

    if (tid < RPB * FOUT) {
        const int r = tid >> 4;
        const int c = tid & 15;
        const float A = red[0][r][c] + red[1][r][c] + red[2][r][c] + red[3][r][c];
        const float L = red[0][r][FOUT] + red[1][r][FOUT] +
                        red[2][r][FOUT] + red[3][r][FOUT];
        const float v = A / L;
        out[(i0 + r) * FOUT + c] = (v > 0.0f) ? v : expm1f(v);   // ELU
    }
}

extern "C" void kernel_launch(void* const* d_in, const int* in_sizes, int n_in,
                              void* d_out, int out_size, void* d_ws, size_t ws_size,
                              hipStream_t stream)
{
    const float* h    = (const float*)d_in[0];
    const int*   adj  = (const int*)d_in[1];
    const float* W    = (const float*)d_in[2];
    const float* attn = (const float*)d_in[3];
    float* out = (float*)d_out;
    float* ws  = (float*)d_ws;

    wh_score_kernel<<<(N * FOUT) / 256, 256, 0, stream>>>(h, W, attn, ws);
    gat_main_kernel<<<N / RPB, 256, 0, stream>>>(adj, ws, out);
}

// Round 4
// 94.655 us; speedup vs baseline: 1.9825x; 1.2193x over previous
//
#include <hip/hip_runtime.h>
#include <hip/hip_bf16.h>
#include <math.h>

#define N      8192
#define FIN    94
#define FOUT   16
#define ALPHA  0.2f
#define BM     64            // rows per block (main kernel)
#define JCH    1024          // j-columns per block (chunked)
#define NCH    (N / JCH)     // 8 chunks
#define NRB    (N / BM)      // 128 row-blocks

// ws layout: bf16 Wh_t[16][8192] at byte 0 (256 KB), then f32 arrays.
#define AR_OFF 65536               // exp(s_src)
#define CR_OFF (AR_OFF + N)        // exp(0.2*s_src)
#define BT_OFF (AR_OFF + 2*N)      // exp(-s_src)
#define BX_OFF (AR_OFF + 3*N)      // exp(s_dst)
#define DX_OFF (AR_OFF + 4*N)      // exp(0.2*s_dst)
#define PN_OFF (AR_OFF + 5*N)            // partial numerators [NCH][N][FOUT]
#define PL_OFF (PN_OFF + NCH*N*FOUT)     // partial denominators [NCH][N]

typedef int   i32x4 __attribute__((ext_vector_type(4)));
typedef float f32x4 __attribute__((ext_vector_type(4)));
typedef short s16x8 __attribute__((ext_vector_type(8)));

// Kernel 1: Wh (bf16, transposed) + all five exp tables.
__global__ __launch_bounds__(256) void wh_score_kernel(
    const float* __restrict__ h, const float* __restrict__ W,
    const float* __restrict__ attn, float* __restrict__ ws)
{
    const int gid = blockIdx.x * 256 + threadIdx.x;  // 0..131071
    const int i = gid >> 4;
    const int k = gid & 15;
    const float* hrow = h + i * FIN;
    float a0 = 0.f, a1 = 0.f, a2 = 0.f, a3 = 0.f;
    #pragma unroll
    for (int c = 0; c < 92; c += 4) {
        a0 = fmaf(hrow[c],     W[c * FOUT + k],       a0);
        a1 = fmaf(hrow[c + 1], W[(c + 1) * FOUT + k], a1);
        a2 = fmaf(hrow[c + 2], W[(c + 2) * FOUT + k], a2);
        a3 = fmaf(hrow[c + 3], W[(c + 3) * FOUT + k], a3);
    }
    a0 = fmaf(hrow[92], W[92 * FOUT + k], a0);
    a1 = fmaf(hrow[93], W[93 * FOUT + k], a1);
    const float acc = (a0 + a1) + (a2 + a3);

    __hip_bfloat16* whtb = (__hip_bfloat16*)ws;
    whtb[k * N + i] = __float2bfloat16(acc);   // transposed bf16 store

    float ps = acc * attn[k];
    float pd = acc * attn[FOUT + k];
    #pragma unroll
    for (int mk = 1; mk < 16; mk <<= 1) {
        ps += __shfl_xor(ps, mk);
        pd += __shfl_xor(pd, mk);
    }
    if (k == 0) {
        // |scores| small: exp() safe in f32, softmax shift-invariant -> no max pass.
        ws[AR_OFF + i] = __expf(ps);
        ws[CR_OFF + i] = __expf(ALPHA * ps);
        ws[BT_OFF + i] = __expf(-ps);
        ws[BX_OFF + i] = __expf(pd);
        ws[DX_OFF + i] = __expf(ALPHA * pd);
    }
}

// Kernel 2 (main): MFMA-based masked-softmax-weighted accumulation.
// Each wave owns 16 rows; per 32-col tile: build P-tile (16x32 bf16) in the
// A-fragment, load Whb tile (32x16 bf16) as B-fragment, one
// mfma_f32_16x16x32_bf16 into the f32x4 accumulator.  j chunked 8x across
// blocks; partial numerator/denominator written to ws.
__global__ __launch_bounds__(256, 4) void gat_mfma_kernel(
    const int* __restrict__ adj, const float* __restrict__ ws,
    float* __restrict__ wso)
{
    __shared__ float Bl[JCH];
    __shared__ float Dl[JCH];

    const int tid = threadIdx.x;
    const int rb = blockIdx.x & (NRB - 1);
    const int ch = blockIdx.x >> 7;          // NRB = 128
    const int i0 = rb * BM;
    const int jc0 = ch * JCH;

    // stage B/D tables for this chunk into LDS (16 B per thread each)
    {
        const int t4 = tid * 4;
        *(f32x4*)(Bl + t4) = *(const f32x4*)(ws + BX_OFF + jc0 + t4);
        *(f32x4*)(Dl + t4) = *(const f32x4*)(ws + DX_OFF + jc0 + t4);
    }
    __syncthreads();

    const int w    = tid >> 6;
    const int lane = tid & 63;
    const int c15  = lane & 15;   // A-row (local), B-col, C-col
    const int g    = lane >> 4;   // k-group: this lane covers k = 8g..8g+7
    const int arow = i0 + w * 16 + c15;          // global A row for this lane

    const float Ar = ws[AR_OFF + arow];
    const float Cr = ws[CR_OFF + arow];
    const float Bt = ws[BT_OFF + arow];

    const unsigned short* __restrict__ whtb = (const unsigned short*)ws;
    const int* __restrict__ ap            = adj + (size_t)arow * N + jc0 + 8 * g;
    const unsigned short* __restrict__ wp = whtb + c15 * N + jc0 + 8 * g;

    f32x4 acc = {0.f, 0.f, 0.f, 0.f};
    float lsum = 0.f;

    i32x4 aA0, aA1, aB0, aB1;
    s16x8 fbA, fbB;

#define ISSUE(A0, A1, FB, t) do {                                              \
    const int off_ = 32 * (t);                                                 \
    (A0) = __builtin_nontemporal_load((const i32x4*)(ap + off_));              \
    (A1) = __builtin_nontemporal_load((const i32x4*)(ap + off_ + 4));          \
    (FB) = *(const s16x8*)(wp + off_);                                         \
} while (0)

    ISSUE(aA0, aA1, fbA, 0);

    #pragma unroll 1
    for (int t = 0; t < JCH / 32; t += 2) {
        ISSUE(aB0, aB1, fbB, t + 1);
        {
            const int lb = t * 32 + 8 * g;
            const f32x4 B0 = *(const f32x4*)(Bl + lb);
            const f32x4 B1 = *(const f32x4*)(Bl + lb + 4);
            const f32x4 D0 = *(const f32x4*)(Dl + lb);
            const f32x4 D1 = *(const f32x4*)(Dl + lb + 4);
            float wf[8];
            #pragma unroll
            for (int e = 0; e < 4; ++e) {
                const bool pos = B0[e] > Bt;
                const float S = pos ? Ar : Cr;
                const float P = pos ? B0[e] : D0[e];
                const float ww = (aA0[e] > 0) ? S * P : 0.0f;
                wf[e] = ww; lsum += ww;
            }
            #pragma unroll
            for (int e = 0; e < 4; ++e) {
                const bool pos = B1[e] > Bt;
                const float S = pos ? Ar : Cr;
                const float P = pos ? B1[e] : D1[e];
                const float ww = (aA1[e] > 0) ? S * P : 0.0f;
                wf[4 + e] = ww; lsum += ww;
            }
            s16x8 fa;
            #pragma unroll
            for (int e = 0; e < 8; ++e) {   // f32 -> bf16 RNE
                const unsigned u = __float_as_uint(wf[e]);
                fa[e] = (short)((u + 0x7fffu + ((u >> 16) & 1u)) >> 16);
            }
            acc = __builtin_amdgcn_mfma_f32_16x16x32_bf16(fa, fbA, acc, 0, 0, 0);
        }
        if (t + 2 < JCH / 32) ISSUE(aA0, aA1, fbA, t + 2);
        {
            const int lb = (t + 1) * 32 + 8 * g;
            const f32x4 B0 = *(const f32x4*)(Bl + lb);
            const f32x4 B1 = *(const f32x4*)(Bl + lb + 4);
            const f32x4 D0 = *(const f32x4*)(Dl + lb);
            const f32x4 D1 = *(const f32x4*)(Dl + lb + 4);
            float wf[8];
            #pragma unroll
            for (int e = 0; e < 4; ++e) {
                const bool pos = B0[e] > Bt;
                const float S = pos ? Ar : Cr;
                const float P = pos ? B0[e] : D0[e];
                const float ww = (aB0[e] > 0) ? S * P : 0.0f;
                wf[e] = ww; lsum += ww;
            }
            #pragma unroll
            for (int e = 0; e < 4; ++e) {
                const bool pos = B1[e] > Bt;
                const float S = pos ? Ar : Cr;
                const float P = pos ? B1[e] : D1[e];
                const float ww = (aB1[e] > 0) ? S * P : 0.0f;
                wf[4 + e] = ww; lsum += ww;
            }
            s16x8 fa;
            #pragma unroll
            for (int e = 0; e < 8; ++e) {
                const unsigned u = __float_as_uint(wf[e]);
                fa[e] = (short)((u + 0x7fffu + ((u >> 16) & 1u)) >> 16);
            }
            acc = __builtin_amdgcn_mfma_f32_16x16x32_bf16(fa, fbB, acc, 0, 0, 0);
        }
    }
#undef ISSUE

    // denominator: reduce lane partials across the 4 k-groups (same row = same lane&15)
    lsum += __shfl_xor(lsum, 16);
    lsum += __shfl_xor(lsum, 32);

    // C/D layout (m89-verified): col = lane&15, row = (lane>>4)*4 + reg
    #pragma unroll
    for (int r = 0; r < 4; ++r) {
        const int grow = i0 + w * 16 + 4 * g + r;
        wso[PN_OFF + ((size_t)ch * N + grow) * FOUT + c15] = acc[r];
    }
    if (g == 0)
        wso[PL_OFF + ch * N + arow] = lsum;
}

// Kernel 3: sum partials over chunks, normalize, ELU.
__global__ __launch_bounds__(256) void reduce_kernel(
    const float* __restrict__ ws, float* __restrict__ out)
{
    const int gid = blockIdx.x * 256 + threadIdx.x;   // 0..131071
    const int i = gid >> 4;
    float num = 0.f, den = 0.f;
    #pragma unroll
    for (int ch = 0; ch < NCH; ++ch) {
        num += ws[PN_OFF + ch * (N * FOUT) + gid - i * FOUT + i * FOUT];  // = PN_OFF + ch*N*FOUT + gid
        den += ws[PL_OFF + ch * N + i];
    }
    const float v = num / den;
    out[gid] = (v > 0.0f) ? v : expm1f(v);   // ELU
}

extern "C" void kernel_launch(void* const* d_in, const int* in_sizes, int n_in,
                              void* d_out, int out_size, void* d_ws, size_t ws_size,
                              hipStream_t stream)
{
    const float* h    = (const float*)d_in[0];
    const int*   adj  = (const int*)d_in[1];
    const float* W    = (const float*)d_in[2];
    const float* attn = (const float*)d_in[3];
    float* out = (float*)d_out;
    float* ws  = (float*)d_ws;

    wh_score_kernel<<<(N * FOUT) / 256, 256, 0, stream>>>(h, W, attn, ws);
    gat_mfma_kernel<<<NRB * NCH, 256, 0, stream>>>(adj, ws, ws);
    reduce_kernel<<<(N * FOUT) / 256, 256, 0, stream>>>(ws, out);
}

// Round 5
// 81.763 us; speedup vs baseline: 2.2951x; 1.1577x over previous
//
#include <hip/hip_runtime.h>
#include <hip/hip_bf16.h>
#include <math.h>

#define N      8192
#define FIN    94
#define FOUT   16
#define ALPHA  0.2f
#define BM     64            // rows per block (main kernel)
#define JCH    1024          // j-columns per block chunk
#define NCH    (N / JCH)     // 8 chunks
#define NRB    (N / BM)      // 128 row-blocks
#define NT     (JCH / 32)    // 32 col-tiles per chunk

// ws layout: bf16 Wh_t[16][8192] at byte 0 (256 KB), then f32 arrays.
#define AR_OFF 65536               // exp(s_src)
#define CR_OFF (AR_OFF + N)        // exp(0.2*s_src)
#define BX_OFF (AR_OFF + 2*N)      // exp(s_dst)
#define DX_OFF (AR_OFF + 3*N)      // exp(0.2*s_dst)
#define PN_OFF (AR_OFF + 4*N)            // partial numerators [NCH][N][FOUT]
#define PL_OFF (PN_OFF + NCH*N*FOUT)     // partial denominators [NCH][N]

typedef int   i32x4 __attribute__((ext_vector_type(4)));
typedef float f32x4 __attribute__((ext_vector_type(4)));
typedef short s16x8 __attribute__((ext_vector_type(8)));

// Kernel 1: Wh (bf16, transposed) + four exp tables.
__global__ __launch_bounds__(256) void wh_score_kernel(
    const float* __restrict__ h, const float* __restrict__ W,
    const float* __restrict__ attn, float* __restrict__ ws)
{
    const int gid = blockIdx.x * 256 + threadIdx.x;  // 0..131071
    const int i = gid >> 4;
    const int k = gid & 15;
    const float* hrow = h + i * FIN;
    float a0 = 0.f, a1 = 0.f, a2 = 0.f, a3 = 0.f;
    #pragma unroll
    for (int c = 0; c < 92; c += 4) {
        a0 = fmaf(hrow[c],     W[c * FOUT + k],       a0);
        a1 = fmaf(hrow[c + 1], W[(c + 1) * FOUT + k], a1);
        a2 = fmaf(hrow[c + 2], W[(c + 2) * FOUT + k], a2);
        a3 = fmaf(hrow[c + 3], W[(c + 3) * FOUT + k], a3);
    }
    a0 = fmaf(hrow[92], W[92 * FOUT + k], a0);
    a1 = fmaf(hrow[93], W[93 * FOUT + k], a1);
    const float acc = (a0 + a1) + (a2 + a3);

    __hip_bfloat16* whtb = (__hip_bfloat16*)ws;
    whtb[k * N + i] = __float2bfloat16(acc);   // transposed bf16 store

    float ps = acc * attn[k];
    float pd = acc * attn[FOUT + k];
    #pragma unroll
    for (int mk = 1; mk < 16; mk <<= 1) {
        ps += __shfl_xor(ps, mk);
        pd += __shfl_xor(pd, mk);
    }
    if (k == 0) {
        // |scores| small: exp() safe in f32, softmax shift-invariant -> no max pass.
        ws[AR_OFF + i] = __expf(ps);
        ws[CR_OFF + i] = __expf(ALPHA * ps);
        ws[BX_OFF + i] = __expf(pd);
        ws[DX_OFF + i] = __expf(ALPHA * pd);
    }
}

// Kernel 2 (main): MFMA masked-softmax-weighted accumulation, depth-4
// register-ring prefetch.  exp(leaky_relu(x)) == max(exp(x), exp(0.2x)).
__global__ __launch_bounds__(256, 4) void gat_mfma_kernel(
    const int* __restrict__ adj, const float* __restrict__ ws,
    float* __restrict__ wso)
{
    __shared__ float Bl[JCH];
    __shared__ float Dl[JCH];

    const int tid = threadIdx.x;
    const int rb = blockIdx.x & (NRB - 1);
    const int ch = blockIdx.x >> 7;          // NRB = 128
    const int i0 = rb * BM;
    const int jc0 = ch * JCH;

    // stage B/D tables for this chunk into LDS
    {
        const int t4 = tid * 4;
        *(f32x4*)(Bl + t4) = *(const f32x4*)(ws + BX_OFF + jc0 + t4);
        *(f32x4*)(Dl + t4) = *(const f32x4*)(ws + DX_OFF + jc0 + t4);
    }
    __syncthreads();

    const int w    = tid >> 6;
    const int lane = tid & 63;
    const int c15  = lane & 15;   // A-row (local), B-col, C-col
    const int g    = lane >> 4;   // k-group: this lane covers k = 8g..8g+7
    const int arow = i0 + w * 16 + c15;

    const float Ar = ws[AR_OFF + arow];
    const float Cr = ws[CR_OFF + arow];

    const unsigned short* __restrict__ whtb = (const unsigned short*)ws;
    const int* __restrict__ ap            = adj + (size_t)arow * N + jc0 + 8 * g;
    const unsigned short* __restrict__ wp = whtb + c15 * N + jc0 + 8 * g;

    f32x4 acc = {0.f, 0.f, 0.f, 0.f};
    float lsum = 0.f;

    i32x4 a0_0, a1_0, a0_1, a1_1, a0_2, a1_2, a0_3, a1_3;
    s16x8 fb_0, fb_1, fb_2, fb_3;

#define ISSUE(s, t) do {                                                       \
    const int off_ = 32 * (t);                                                 \
    a0_##s = __builtin_nontemporal_load((const i32x4*)(ap + off_));            \
    a1_##s = __builtin_nontemporal_load((const i32x4*)(ap + off_ + 4));        \
    fb_##s = *(const s16x8*)(wp + off_);                                       \
} while (0)

#define COMPUTE(s, t) do {                                                     \
    const int lb = (t) * 32 + 8 * g;                                           \
    const f32x4 B0 = *(const f32x4*)(Bl + lb);                                 \
    const f32x4 B1 = *(const f32x4*)(Bl + lb + 4);                             \
    const f32x4 D0 = *(const f32x4*)(Dl + lb);                                 \
    const f32x4 D1 = *(const f32x4*)(Dl + lb + 4);                             \
    float wf[8];                                                               \
    _Pragma("unroll") for (int e = 0; e < 4; ++e) {                            \
        const float ww = (a0_##s[e] > 0) ?                                     \
            fmaxf(Ar * B0[e], Cr * D0[e]) : 0.0f;                              \
        wf[e] = ww; lsum += ww;                                                \
    }                                                                          \
    _Pragma("unroll") for (int e = 0; e < 4; ++e) {                            \
        const float ww = (a1_##s[e] > 0) ?                                     \
            fmaxf(Ar * B1[e], Cr * D1[e]) : 0.0f;                              \
        wf[4 + e] = ww; lsum += ww;                                            \
    }                                                                          \
    s16x8 fa;                                                                  \
    _Pragma("unroll") for (int e = 0; e < 8; ++e)                              \
        fa[e] = (short)__builtin_bit_cast(unsigned short,                      \
                                          __float2bfloat16(wf[e]));           \
    acc = __builtin_amdgcn_mfma_f32_16x16x32_bf16(fa, fb_##s, acc, 0, 0, 0);   \
} while (0)

    ISSUE(0, 0); ISSUE(1, 1); ISSUE(2, 2); ISSUE(3, 3);

    #pragma unroll 1
    for (int t = 0; t < NT - 4; t += 4) {
        COMPUTE(0, t);     ISSUE(0, t + 4);
        COMPUTE(1, t + 1); ISSUE(1, t + 5);
        COMPUTE(2, t + 2); ISSUE(2, t + 6);
        COMPUTE(3, t + 3); ISSUE(3, t + 7);
    }
    COMPUTE(0, NT - 4); COMPUTE(1, NT - 3); COMPUTE(2, NT - 2); COMPUTE(3, NT - 1);
#undef ISSUE
#undef COMPUTE

    // denominator: reduce lane partials across the 4 k-groups
    lsum += __shfl_xor(lsum, 16);
    lsum += __shfl_xor(lsum, 32);

    // C/D layout (m89-verified): col = lane&15, row = (lane>>4)*4 + reg
    #pragma unroll
    for (int r = 0; r < 4; ++r) {
        const int grow = i0 + w * 16 + 4 * g + r;
        wso[PN_OFF + ((size_t)ch * N + grow) * FOUT + c15] = acc[r];
    }
    if (g == 0)
        wso[PL_OFF + ch * N + arow] = lsum;
}

// Kernel 3: sum partials over chunks, normalize, ELU.
__global__ __launch_bounds__(256) void reduce_kernel(
    const float* __restrict__ ws, float* __restrict__ out)
{
    const int gid = blockIdx.x * 256 + threadIdx.x;   // 0..131071
    const int i = gid >> 4;
    float num = 0.f, den = 0.f;
    #pragma unroll
    for (int ch = 0; ch < NCH; ++ch) {
        num += ws[PN_OFF + (size_t)ch * (N * FOUT) + gid];
        den += ws[PL_OFF + ch * N + i];
    }
    const float v = num / den;
    out[gid] = (v > 0.0f) ? v : expm1f(v);   // ELU
}

extern "C" void kernel_launch(void* const* d_in, const int* in_sizes, int n_in,
                              void* d_out, int out_size, void* d_ws, size_t ws_size,
                              hipStream_t stream)
{
    const float* h    = (const float*)d_in[0];
    const int*   adj  = (const int*)d_in[1];
    const float* W    = (const float*)d_in[2];
    const float* attn = (const float*)d_in[3];
    float* out = (float*)d_out;
    float* ws  = (float*)d_ws;

    wh_score_kernel<<<(N * FOUT) / 256, 256, 0, stream>>>(h, W, attn, ws);
    gat_mfma_kernel<<<NRB * NCH, 256, 0, stream>>>(adj, ws, ws);
    reduce_kernel<<<(N * FOUT) / 256, 256, 0, stream>>>(ws, out);
}